// Round 10
// baseline (107.391 us; speedup 1.0000x reference)
//
#include <hip/hip_runtime.h>
#include <hip/hip_bf16.h>

#define DIM  512
#define FEAT 64
#define BATCH 2048

#define ROWS_PER_BLOCK 256
#define TILES 16           // ROWS_PER_BLOCK / 16 (all 4 waves share the tile schedule)

using bf16x8 = __attribute__((ext_vector_type(8))) short;
using f32x4  = __attribute__((ext_vector_type(4))) float;

typedef __attribute__((address_space(3))) float lds_f;
typedef __attribute__((address_space(1))) const float glb_f;

__device__ inline short f2bf(float f) {
    unsigned int u = __float_as_uint(f);
    u += 0x7fffu + ((u >> 16) & 1u);
    return (short)(u >> 16);
}

__device__ inline bf16x8 cvt8(float4 a, float4 b) {
    bf16x8 r;
    r[0] = f2bf(a.x); r[1] = f2bf(a.y); r[2] = f2bf(a.z); r[3] = f2bf(a.w);
    r[4] = f2bf(b.x); r[5] = f2bf(b.y); r[6] = f2bf(b.z); r[7] = f2bf(b.w);
    return r;
}

// Block owns 4 CONSECUTIVE d (one per wave) and a 256-row range; the 4 waves run the
// same 16-row tile schedule in lockstep (s_barrier) so the block's combined traffic is
// 16 rows x 1KB-contiguous islands (4 adjacent d x 256B) instead of 256B islands.
// launch_bounds arg2=3: VGPR cap ~85, kernel needs ~52-72 (R9-verified, no spill).
__global__ __launch_bounds__(256, 3)
void split_linear_kernel(const float* __restrict__ x,
                         const float* __restrict__ W,
                         const float* __restrict__ bias,
                         float* __restrict__ out)
{
    // x staging AND out-transpose share slots: [wave][slot][16 rows][16 chunks],
    // 16B-chunk XOR(row&7) swizzle on both paths (R8/R9-verified).
    __shared__ float xlds[4][2][1024];
    __shared__ float blds[4][FEAT];

    // XCD swizzle: consecutive d-groups on one XCD (write/L2 locality).
    const int id    = blockIdx.x;          // 0..1023
    const int xcd   = id & 7;
    const int chunk = id >> 3;             // 0..127
    const int nid   = xcd * 128 + chunk;   // 0..1023
    const int dg    = nid & 127;           // d-group (4 consecutive d)
    const int rc    = nid >> 7;            // row-chunk 0..7
    const int b0    = rc * ROWS_PER_BLOCK;

    const int tid  = threadIdx.x;
    const int wave = tid >> 6;
    const int lane = tid & 63;
    const int lr   = lane & 15;   // A-row (g) / B-col (batch row)
    const int lk   = lane >> 4;   // k-group / D row-quad
    const int d    = dg * 4 + wave;        // THIS wave's slice

    // bias into wave-private LDS (per-wave DS ordering; no block sync needed)
    blds[wave][lane] = bias[(size_t)d * FEAT + lane];

    // ---- W fragments in registers ----
    bf16x8 wf[2][4];
#pragma unroll
    for (int mt = 0; mt < 4; ++mt) {
        const float* wrow = W + ((size_t)d * FEAT + mt * 16 + lr) * FEAT + lk * 8;
#pragma unroll
        for (int ks = 0; ks < 2; ++ks) {
            float4 w0 = *(const float4*)(wrow + ks * 32);
            float4 w1 = *(const float4*)(wrow + ks * 32 + 4);
            wf[ks][mt] = cvt8(w0, w1);
        }
    }

    // ---- async dense stage: 4 instrs, each 4 rows x 256B fully covered ----
    auto stage = [&](int slot, int tt) {
#pragma unroll
        for (int i = 0; i < 4; ++i) {
            const int r = i * 4 + (lane >> 4);
            const int c = (lane & 15) ^ (r & 7);   // pre-swizzled source chunk
            const float* gp = x + ((size_t)(b0 + tt * 16 + r) * DIM + d) * FEAT + c * 4;
            __builtin_amdgcn_global_load_lds((glb_f*)gp,
                                             (lds_f*)&xlds[wave][slot][i * 256],
                                             16, 0, 0);
        }
    };

    stage(0, 0);            // tile 0
    stage(1, 1);            // tile 1

    for (int t = 0; t < TILES; ++t) {
        const int s = t & 1;
        // timing-only barrier: keeps the 4 waves' stage/store bursts coincident so the
        // block's islands merge into 1KB DRAM-row runs. LDS slots are wave-private,
        // so no data crosses the barrier (raw s_barrier, counted vmcnt preserved).
        __builtin_amdgcn_s_barrier();
        // in-order vmcnt retirement (R9-verified schedule):
        // steady outstanding: st(t-2),stage(t),st(t-1),stage(t+1) = 16 -> vmcnt(8)
        if (t == 0 || t == TILES - 1)
            asm volatile("s_waitcnt vmcnt(4)" ::: "memory");
        else
            asm volatile("s_waitcnt vmcnt(8)" ::: "memory");
        __builtin_amdgcn_sched_barrier(0);

        float* sl = &xlds[wave][s][0];
        float4 p0a = *(const float4*)&sl[lr * 64 + (((lk * 2 + 0) ^ (lr & 7)) << 2)];
        float4 p0b = *(const float4*)&sl[lr * 64 + (((lk * 2 + 1) ^ (lr & 7)) << 2)];
        float4 p1a = *(const float4*)&sl[lr * 64 + (((8 + lk * 2 + 0) ^ (lr & 7)) << 2)];
        float4 p1b = *(const float4*)&sl[lr * 64 + (((8 + lk * 2 + 1) ^ (lr & 7)) << 2)];

        bf16x8 af0 = cvt8(p0a, p0b);   // ks = 0
        bf16x8 af1 = cvt8(p1a, p1b);   // ks = 1

        f32x4 acc[4];
#pragma unroll
        for (int mt = 0; mt < 4; ++mt)
            acc[mt] = *(const f32x4*)&blds[wave][mt * 16 + lk * 4];
#pragma unroll
        for (int mt = 0; mt < 4; ++mt)
            acc[mt] = __builtin_amdgcn_mfma_f32_16x16x32_bf16(wf[0][mt], af0, acc[mt], 0, 0, 0);
#pragma unroll
        for (int mt = 0; mt < 4; ++mt)
            acc[mt] = __builtin_amdgcn_mfma_f32_16x16x32_bf16(wf[1][mt], af1, acc[mt], 0, 0, 0);

        // ---- transpose INTO the just-consumed slot (wave-private, DS in-order) ----
#pragma unroll
        for (int mt = 0; mt < 4; ++mt) {
            const int c  = mt * 4 + lk;
            const int pc = c ^ (lr & 7);           // same swizzle as stage
            *(f32x4*)&sl[lr * 64 + pc * 4] = acc[mt];
        }

        // ---- dense NT store-back: instr j covers rows j*4..+3, full 256B per row;
        //      the block's 4 waves together cover 1KB contiguous per row ----
        const int orow0 = b0 + t * 16;
#pragma unroll
        for (int j = 0; j < 4; ++j) {
            const int rr  = j * 4 + (lane >> 4);
            const int cc  = lane & 15;
            const int pc2 = cc ^ (rr & 7);
            f32x4 v = *(const f32x4*)&sl[rr * 64 + pc2 * 4];
            __builtin_nontemporal_store(v,
                (f32x4*)(out + ((size_t)(orow0 + rr) * DIM + d) * FEAT + cc * 4));
        }
        __builtin_amdgcn_sched_barrier(0);   // pin the re-stage below the stores

        if (t + 2 < TILES)
            stage(s, t + 2);                 // reuse slot s (DMA lands after ds_reads)
    }
}

extern "C" void kernel_launch(void* const* d_in, const int* in_sizes, int n_in,
                              void* d_out, int out_size, void* d_ws, size_t ws_size,
                              hipStream_t stream) {
    const float* x    = (const float*)d_in[0];
    const float* W    = (const float*)d_in[1];
    const float* bias = (const float*)d_in[2];
    float* out        = (float*)d_out;

    dim3 grid((DIM / 4) * (BATCH / ROWS_PER_BLOCK), 1, 1);  // 128 * 8 = 1024 blocks
    dim3 block(256, 1, 1);
    split_linear_kernel<<<grid, block, 0, stream>>>(x, W, bias, out);
}